// Round 6
// baseline (569.698 us; speedup 1.0000x reference)
//
#include <hip/hip_runtime.h>

typedef unsigned long long u64;

// x [32,256,32,32] f32, w [256,256,3,3] f32; reduction R = 2304 = 36 x 64.
#define NPIX   32768
#define OCH    256
#define NCH    36

// stage 0: zero stats; build the 9 boundary-class chunk masks.
__global__ void bb_init(float* st, u64* masks) {
  int t = threadIdx.x;
  for (int i = t; i < 1024; i += 256) st[i] = 0.f;
  for (int id = t; id < 9 * NCH; id += 256) {
    int cls = id / NCH, ck = id % NCH;
    int ch = cls / 3, cw = cls % 3;
    u64 m = 0;
    for (int b = 0; b < 64; ++b) {
      int r = ck * 64 + b, tap = r % 9, kh = tap / 3, kw = tap % 3;
      bool oob = (ch == 0 && kh == 0) || (ch == 2 && kh == 2) ||
                 (cw == 0 && kw == 0) || (cw == 2 && kw == 2);
      if (!oob) m |= (u64)1 << b;
    }
    masks[id] = m;
  }
}

// stage 1: weight sign bits Wbits[layer][oc][chunk].
__global__ void bb_wbits(const float* wa, const float* wb, u64* Wbits) {
  int word = (blockIdx.x * blockDim.x + threadIdx.x) >> 6;
  int ln = threadIdx.x & 63;
  if (word >= 2 * OCH * NCH) return;
  const float* src = (word < OCH * NCH) ? wa : wb;
  int r = word % (OCH * NCH);
  u64 bits = __ballot(src[(size_t)r * 64 + ln] >= 0.f);
  if (ln == 0) Wbits[word] = bits;
}

// stage 2: x0 sign bitplanes Sb[pixel][word] (bit = channel within word).
__global__ void bb_xbits(const float* x, u64* Sb) {
  int wave = (blockIdx.x * blockDim.x + threadIdx.x) >> 6;
  int ln = threadIdx.x & 63;
  int h = wave & 31, wrd = (wave >> 5) & 3, n = wave >> 7;
  int c = wrd * 64 + ln;
  const float* row = x + ((size_t)((n * 256 + c) * 32 + h) << 5);
  #pragma unroll 4
  for (int w = 0; w < 32; ++w) {
    u64 bits = __ballot(row[w] >= 0.f);
    if (ln == 0) Sb[(size_t)((n * 32 + h) * 32 + w) * 4 + wrd] = bits;
  }
}

// stage 3: patch words Pw[pixel][36]; bit b of chunk i is reduction index
// r = 64i+b, channel r/9, tap r%9. Per tap: extract a 7/8-bit channel run,
// spread to stride-9 bit positions via LDS LUT.
__global__ void bb_patch(const u64* Sb, u64* Pw) {
  __shared__ u64 spread[256];
  for (int e = threadIdx.x; e < 256; e += blockDim.x) {
    u64 v = 0;
    for (int k = 0; k < 8; ++k) if (e & (1 << k)) v |= (u64)1 << (9 * k);
    spread[e] = v;
  }
  __syncthreads();
  int tid = blockIdx.x * blockDim.x + threadIdx.x;
  if (tid >= NPIX * NCH) return;
  int ck = tid % NCH, px = tid / NCH;
  int n = px >> 10, h = (px >> 5) & 31, w = px & 31;
  int base9 = ck % 9;
  u64 acc = 0;
  for (int t = 0; t < 9; ++t) {
    int b0 = t - base9; if (b0 < 0) b0 += 9;
    int nh = h + t / 3 - 1, nw = w + (t % 3) - 1;
    if ((unsigned)nh > 31u || (unsigned)nw > 31u) continue;
    int run = (b0 == 0) ? 8 : 7;
    int c0 = (ck * 64 + b0) / 9;
    const u64* rp = Sb + ((size_t)((n * 32 + nh) * 32 + nw) << 2);
    int wi = c0 >> 6, sh = c0 & 63;
    u64 v = rp[wi] >> sh;
    if (sh + run > 64) v |= rp[wi + 1] << (64 - sh);
    v &= (run == 8) ? 0xFFull : 0x7Full;
    acc |= spread[(int)v] << b0;
  }
  Pw[tid] = acc;
}

// stage 4: XNOR-popcount conv. Interior: psums even -> quantizer identity ->
// acc = 2304 - 2*sum(popc). Boundary: ps = inb - 2*miss, round-half-even:
// q = ps + (ps&1)*((ps&2)-1). Acc clip +/-254 (inert; kept for fidelity).
__global__ __launch_bounds__(256) void bb_conv(
    const u64* __restrict__ Pw, const u64* __restrict__ Wbits,
    const u64* __restrict__ masks, short* dst16, float* dstf,
    const float* resid, int phase) {
  __shared__ u64 wl[64 * NCH];
  int og = blockIdx.y;
  const u64* wsrc = Wbits + (size_t)og * 64 * NCH;
  for (int i = threadIdx.x; i < 64 * NCH; i += 256) wl[i] = wsrc[i];
  __syncthreads();
  int ln = threadIdx.x & 63, wv = threadIdx.x >> 6;
  u64 wr[NCH];
  #pragma unroll
  for (int i = 0; i < NCH; ++i) wr[i] = wl[ln * NCH + i];
  int oc = og * 64 + ln;
  int row0 = blockIdx.x * 128 + wv * 32;
  row0 = __builtin_amdgcn_readfirstlane(row0);
  int n = row0 >> 10, h = (row0 >> 5) & 31;
  for (int j = 0; j < 32; ++j) {
    int px = row0 + j;
    const u64* xr = Pw + (size_t)px * NCH;
    int acc;
    if (h > 0 && h < 31 && j > 0 && j < 31) {
      int D = 0;
      #pragma unroll
      for (int i = 0; i < NCH; ++i) D += __popcll(xr[i] ^ wr[i]);
      acc = 2304 - 2 * D;
    } else {
      int cls = (h == 0 ? 0 : (h == 31 ? 2 : 1)) * 3 + (j == 0 ? 0 : (j == 31 ? 2 : 1));
      const u64* mr = masks + cls * NCH;
      acc = 0;
      #pragma unroll
      for (int i = 0; i < NCH; ++i) {
        u64 m = mr[i];
        int d = __popcll((xr[i] ^ wr[i]) & m);
        int ps = __popcll(m) - 2 * d;
        acc += ps + (ps & 1) * ((ps & 2) - 1);
      }
    }
    acc = acc < -254 ? -254 : (acc > 254 ? 254 : acc);
    if (phase == 1) {
      dst16[(size_t)px * OCH + oc] = (short)acc;
    } else {
      size_t oi = ((size_t)(n * 256 + oc) * 32 + h) * 32 + j;
      dstf[oi] = (float)acc + resid[oi];
    }
  }
}

// stage 5: BN1 batch stats. Per-block partial sums are exact integers in f32;
// the value-sum chain stays < 2^24 so atomic order cannot change it. The
// sq-sum's low-order rounding only perturbs var1, which never affects any
// downstream sign (gamma1 scale only), so output stays deterministic.
__global__ void bb_stats1(const short* v16, float* st) {
  int t = threadIdx.x;
  const short* base = v16 + (size_t)blockIdx.x * 128 * OCH;
  int s = 0; float q = 0.f;
  for (int r = 0; r < 128; ++r) {
    int v = base[r * OCH + t];
    s += v; q += (float)(v * v);
  }
  atomicAdd(&st[t], (float)s);
  atomicAdd(&st[256 + t], q);
}

// stage 6: BN1 + hardtanh + sign-pack (hardtanh preserves sign).
__global__ void bb_xbits2(const short* v16, const float* st,
                          const float* g, const float* b, u64* Sb) {
  int wave = (blockIdx.x * blockDim.x + threadIdx.x) >> 6;
  int ln = threadIdx.x & 63;
  int wrd = wave & 3, px0 = (wave >> 2) * 32;
  int oc = wrd * 64 + ln;
  float mu = st[oc] * (1.f / 32768.f);
  float va = st[256 + oc] * (1.f / 32768.f) - mu * mu;
  float rs = rsqrtf(va + 1e-5f);
  float gg = g[oc], bb = b[oc];
  for (int j = 0; j < 32; ++j) {
    float bn = ((float)v16[(size_t)(px0 + j) * OCH + oc] - mu) * rs * gg + bb;
    u64 bits = __ballot(bn >= 0.f);
    if (ln == 0) Sb[(size_t)(px0 + j) * 4 + wrd] = bits;
  }
}

// stage 7: BN2 batch stats (deterministic block reduction, no atomics).
__global__ void bb_stats2(const float* p, float* st) {
  int oc = blockIdx.x, t = threadIdx.x;
  float s = 0.f, q = 0.f;
  for (int n = 0; n < 32; ++n) {
    const float* base = p + ((size_t)(n * 256 + oc) << 10);
    for (int k = t; k < 1024; k += 256) { float v = base[k]; s += v; q += v * v; }
  }
  __shared__ float sm[256], qm[256];
  sm[t] = s; qm[t] = q; __syncthreads();
  for (int o = 128; o > 0; o >>= 1) {
    if (t < o) { sm[t] += sm[t + o]; qm[t] += qm[t + o]; }
    __syncthreads();
  }
  if (t == 0) { st[512 + oc] = sm[0]; st[768 + oc] = qm[0]; }
}

// stage 8: BN2 + hardtanh + store; reg output is data-independent:
// per conv r = (120*24 + 4*16)/1024 = 2.875; reg = reg0 + r1 + 2*r2.
__global__ void bb_fin(const float* p, const float* st,
                       const float* g, const float* b,
                       const float* r0, float* out) {
  size_t i = (size_t)blockIdx.x * blockDim.x + threadIdx.x;
  if (i == 0) out[8388608] = r0[0] + 8.625f;
  if (i >= 8388608) return;
  int oc = (int)((i >> 10) & 255);
  float mu = st[512 + oc] * (1.f / 32768.f);
  float va = st[768 + oc] * (1.f / 32768.f) - mu * mu;
  float rs = rsqrtf(va + 1e-5f);
  float v = (p[i] - mu) * rs * g[oc] + b[oc];
  out[i] = fminf(fmaxf(v, -1.f), 1.f);
}

extern "C" void kernel_launch(void* const* d_in, const int* in_sizes, int n_in,
                              void* d_out, int out_size, void* d_ws, size_t ws_size,
                              hipStream_t stream) {
  const float* x0   = (const float*)d_in[0];
  const float* reg0 = (const float*)d_in[1];
  const float* w1   = (const float*)d_in[2];
  const float* g1   = (const float*)d_in[3];
  const float* b1   = (const float*)d_in[4];
  const float* w2   = (const float*)d_in[5];
  const float* g2   = (const float*)d_in[6];
  const float* b2   = (const float*)d_in[7];

  char* ws = (char*)d_ws;
  u64*   Wbits = (u64*)(ws);                        // 147456 B
  u64*   masks = (u64*)(ws + 147456);               // 2592 B
  float* st    = (float*)(ws + 151552);             // 4 KiB
  u64*   Sb    = (u64*)(ws + 155648);               // 1 MiB
  u64*   Pw    = (u64*)(ws + 155648 + 1048576);     // 9.44 MB
  char*  big   = ws + 155648 + 1048576 + 9437184;   // 33.6 MB: v16 / pre
  short* v16   = (short*)big;
  float* pre   = (float*)big;

  bb_init  <<<1,    256, 0, stream>>>(st, masks);
  bb_wbits <<<4608, 256, 0, stream>>>(w1, w2, Wbits);
  bb_xbits <<<1024, 256, 0, stream>>>(x0, Sb);
  bb_patch <<<4608, 256, 0, stream>>>(Sb, Pw);
  bb_conv  <<<dim3(256, 4), 256, 0, stream>>>(Pw, Wbits, masks, v16, nullptr, nullptr, 1);
  bb_stats1<<<256,  256, 0, stream>>>(v16, st);
  bb_xbits2<<<1024, 256, 0, stream>>>(v16, st, g1, b1, Sb);
  bb_patch <<<4608, 256, 0, stream>>>(Sb, Pw);
  bb_conv  <<<dim3(256, 4), 256, 0, stream>>>(Pw, Wbits + OCH * NCH, masks, nullptr, pre, x0, 2);
  bb_stats2<<<256,  256, 0, stream>>>(pre, st);
  bb_fin   <<<32769, 256, 0, stream>>>(pre, st, g2, b2, reg0, (float*)d_out);
}

// Round 7
// 405.545 us; speedup vs baseline: 1.4048x; 1.4048x over previous
//
#include <hip/hip_runtime.h>

typedef unsigned long long u64;
typedef __attribute__((ext_vector_type(4))) unsigned long long u64x4;

// x [32,256,32,32] f32, w [256,256,3,3] f32; reduction R = 2304 = 36 x 64.
#define NPIX   32768
#define OCH    256
#define NCH    36

// stage 0: zero stats; build the 9 boundary-class chunk masks.
__global__ void bb_init(float* st, u64* masks) {
  int t = threadIdx.x;
  for (int i = t; i < 1024; i += 256) st[i] = 0.f;
  for (int id = t; id < 9 * NCH; id += 256) {
    int cls = id / NCH, ck = id % NCH;
    int ch = cls / 3, cw = cls % 3;
    u64 m = 0;
    for (int b = 0; b < 64; ++b) {
      int r = ck * 64 + b, tap = r % 9, kh = tap / 3, kw = tap % 3;
      bool oob = (ch == 0 && kh == 0) || (ch == 2 && kh == 2) ||
                 (cw == 0 && kw == 0) || (cw == 2 && kw == 2);
      if (!oob) m |= (u64)1 << b;
    }
    masks[id] = m;
  }
}

// stage 1: weight sign bits Wbits[layer][oc][chunk].
__global__ void bb_wbits(const float* wa, const float* wb, u64* Wbits) {
  int word = (blockIdx.x * blockDim.x + threadIdx.x) >> 6;
  int ln = threadIdx.x & 63;
  if (word >= 2 * OCH * NCH) return;
  const float* src = (word < OCH * NCH) ? wa : wb;
  int r = word % (OCH * NCH);
  u64 bits = __ballot(src[(size_t)r * 64 + ln] >= 0.f);
  if (ln == 0) Wbits[word] = bits;
}

// stage 2: x0 sign bitplanes Sb[pixel][word] (bit = channel within word).
__global__ void bb_xbits(const float* x, u64* Sb) {
  int wave = (blockIdx.x * blockDim.x + threadIdx.x) >> 6;
  int ln = threadIdx.x & 63;
  int h = wave & 31, wrd = (wave >> 5) & 3, n = wave >> 7;
  int c = wrd * 64 + ln;
  const float* row = x + ((size_t)((n * 256 + c) * 32 + h) << 5);
  #pragma unroll 4
  for (int w = 0; w < 32; ++w) {
    u64 bits = __ballot(row[w] >= 0.f);
    if (ln == 0) Sb[(size_t)((n * 32 + h) * 32 + w) * 4 + wrd] = bits;
  }
}

// stage 3: patch words Pw[pixel][36]; bit b of chunk i is reduction index
// r = 64i+b, channel r/9, tap r%9. Per tap: extract a 7/8-bit channel run,
// spread to stride-9 bit positions via LDS LUT.
__global__ void bb_patch(const u64* Sb, u64* Pw) {
  __shared__ u64 spread[256];
  for (int e = threadIdx.x; e < 256; e += blockDim.x) {
    u64 v = 0;
    for (int k = 0; k < 8; ++k) if (e & (1 << k)) v |= (u64)1 << (9 * k);
    spread[e] = v;
  }
  __syncthreads();
  int tid = blockIdx.x * blockDim.x + threadIdx.x;
  if (tid >= NPIX * NCH) return;
  int ck = tid % NCH, px = tid / NCH;
  int n = px >> 10, h = (px >> 5) & 31, w = px & 31;
  int base9 = ck % 9;
  u64 acc = 0;
  for (int t = 0; t < 9; ++t) {
    int b0 = t - base9; if (b0 < 0) b0 += 9;
    int nh = h + t / 3 - 1, nw = w + (t % 3) - 1;
    if ((unsigned)nh > 31u || (unsigned)nw > 31u) continue;
    int run = (b0 == 0) ? 8 : 7;
    int c0 = (ck * 64 + b0) / 9;
    const u64* rp = Sb + ((size_t)((n * 32 + nh) * 32 + nw) << 2);
    int wi = c0 >> 6, sh = c0 & 63;
    u64 v = rp[wi] >> sh;
    if (sh + run > 64) v |= rp[wi + 1] << (64 - sh);
    v &= (run == 8) ? 0xFFull : 0x7Full;
    acc |= spread[(int)v] << b0;
  }
  Pw[tid] = acc;
}

// stage 4: XNOR-popcount conv -> short [px][oc].
// Interior: psums even -> quantizer identity -> acc = 2304 - 2*sum(popc).
// Boundary (edge waves only): ps = inb - 2*miss, round-half-even:
// q = ps + (ps&1)*((ps&2)-1).  Acc clip +/-254 inert but kept.
// W held in 9 named u64x4 registers (NOT an indexed array -> no scratch spill;
// round-6 counters showed VGPR=44 + 528MB scratch FETCH from the spilled wr[36]).
__global__ __launch_bounds__(256) void bb_conv(
    const u64* __restrict__ Pw, const u64* __restrict__ Wbits,
    const u64* __restrict__ masks, short* __restrict__ dst) {
  __shared__ u64 wl[64 * NCH];
  int og = blockIdx.y;
  const u64* wsrc = Wbits + (size_t)og * 64 * NCH;
  for (int i = threadIdx.x; i < 64 * NCH; i += 256) wl[i] = wsrc[i];
  __syncthreads();
  int ln = threadIdx.x & 63, wv = threadIdx.x >> 6;
  const u64x4* wp = (const u64x4*)(wl + ln * NCH);   // ln*288B: 32B aligned
  u64x4 W0 = wp[0], W1 = wp[1], W2 = wp[2], W3 = wp[3], W4 = wp[4],
        W5 = wp[5], W6 = wp[6], W7 = wp[7], W8 = wp[8];
  int oc = og * 64 + ln;
  int row0 = blockIdx.x * 128 + wv * 32;
  row0 = __builtin_amdgcn_readfirstlane(row0);
  int h = (row0 >> 5) & 31;
  for (int j = 0; j < 32; ++j) {
    int px = row0 + j;
    int acc;
    if (h > 0 && h < 31 && j > 0 && j < 31) {
      const u64x4* xp = (const u64x4*)(Pw + (size_t)px * NCH);
      int D = 0;
      #define ACC4(Wv, g) do { u64x4 xv = xp[g]; \
        D += __popcll(xv[0] ^ (Wv)[0]); D += __popcll(xv[1] ^ (Wv)[1]); \
        D += __popcll(xv[2] ^ (Wv)[2]); D += __popcll(xv[3] ^ (Wv)[3]); } while (0)
      ACC4(W0, 0); ACC4(W1, 1); ACC4(W2, 2); ACC4(W3, 3); ACC4(W4, 4);
      ACC4(W5, 5); ACC4(W6, 6); ACC4(W7, 7); ACC4(W8, 8);
      #undef ACC4
      acc = 2304 - 2 * D;
    } else {
      int cls = (h == 0 ? 0 : (h == 31 ? 2 : 1)) * 3 + (j == 0 ? 0 : (j == 31 ? 2 : 1));
      const u64* mr = masks + cls * NCH;
      const u64* xr = Pw + (size_t)px * NCH;
      const u64* wr = wl + ln * NCH;        // boundary is rare: read W from LDS
      acc = 0;
      for (int i = 0; i < NCH; ++i) {
        u64 m = mr[i];
        int d = __popcll((xr[i] ^ wr[i]) & m);
        int ps = __popcll(m) - 2 * d;
        acc += ps + (ps & 1) * ((ps & 2) - 1);
      }
    }
    acc = acc < -254 ? -254 : (acc > 254 ? 254 : acc);
    dst[(size_t)px * OCH + oc] = (short)acc;
  }
}

// stage 5: BN1 batch stats (integer values -> exact f32 sums).
__global__ void bb_stats1(const short* v16, float* st) {
  int t = threadIdx.x;
  const short* base = v16 + (size_t)blockIdx.x * 128 * OCH;
  int s = 0; float q = 0.f;
  for (int r = 0; r < 128; ++r) {
    int v = base[r * OCH + t];
    s += v; q += (float)(v * v);
  }
  atomicAdd(&st[t], (float)s);
  atomicAdd(&st[256 + t], q);
}

// stage 6: BN1 + hardtanh + sign-pack (hardtanh preserves sign).
__global__ void bb_xbits2(const short* v16, const float* st,
                          const float* g, const float* b, u64* Sb) {
  int wave = (blockIdx.x * blockDim.x + threadIdx.x) >> 6;
  int ln = threadIdx.x & 63;
  int wrd = wave & 3, px0 = (wave >> 2) * 32;
  int oc = wrd * 64 + ln;
  float mu = st[oc] * (1.f / 32768.f);
  float va = st[256 + oc] * (1.f / 32768.f) - mu * mu;
  float rs = rsqrtf(va + 1e-5f);
  float gg = g[oc], bb = b[oc];
  for (int j = 0; j < 32; ++j) {
    float bn = ((float)v16[(size_t)(px0 + j) * OCH + oc] - mu) * rs * gg + bb;
    u64 bits = __ballot(bn >= 0.f);
    if (ln == 0) Sb[(size_t)(px0 + j) * 4 + wrd] = bits;
  }
}

// stage 7: BN2 batch stats of (conv2 + residual). Block = one (n,h) row-tile.
// x0 is staged through a padded LDS transpose so both the NCHW x0 reads
// (w-contiguous) and the [px][oc] pre16 reads (oc-contiguous) coalesce.
__global__ __launch_bounds__(256) void bb_stats2t(const short* __restrict__ pre16,
                                                  const float* __restrict__ x0,
                                                  float* st) {
  __shared__ float xt[32][257];
  int blk = blockIdx.x;                 // blk = n*32 + h
  int n = blk >> 5, h = blk & 31;
  int t = threadIdx.x;
  int w = t & 31, og = t >> 5;          // 8 oc-groups
  for (int k = 0; k < 32; ++k) {
    int oc = og * 32 + k;
    xt[w][oc] = x0[((size_t)(n * 256 + oc) * 32 + h) * 32 + w];
  }
  __syncthreads();
  int oc = t;
  size_t pb = (size_t)blk * 32 * OCH + oc;
  float s = 0.f, q = 0.f;
  for (int w2 = 0; w2 < 32; ++w2) {
    float v = (float)pre16[pb + (size_t)w2 * OCH] + xt[w2][oc];
    s += v; q += v * v;
  }
  atomicAdd(&st[512 + oc], s);
  atomicAdd(&st[768 + oc], q);
}

// stage 8: BN2 + hardtanh + NCHW store via in-place LDS transpose;
// reg output is data-independent: r = (120*24+4*16)/1024 = 2.875 per conv,
// reg = reg0 + r1 + 2*r2 = reg0 + 8.625.
__global__ __launch_bounds__(256) void bb_fint(const short* __restrict__ pre16,
                                               const float* __restrict__ x0,
                                               const float* st, const float* g,
                                               const float* b, const float* r0,
                                               float* __restrict__ out) {
  __shared__ float xt[32][257];
  int blk = blockIdx.x;
  int n = blk >> 5, h = blk & 31;
  int t = threadIdx.x;
  int w = t & 31, og = t >> 5;
  for (int k = 0; k < 32; ++k) {
    int oc = og * 32 + k;
    xt[w][oc] = x0[((size_t)(n * 256 + oc) * 32 + h) * 32 + w];
  }
  __syncthreads();
  int oc = t;
  float mu = st[512 + oc] * (1.f / 32768.f);
  float va = st[768 + oc] * (1.f / 32768.f) - mu * mu;
  float rs = rsqrtf(va + 1e-5f);
  float gg = g[oc], bb = b[oc];
  size_t pb = (size_t)blk * 32 * OCH + oc;
  for (int w2 = 0; w2 < 32; ++w2) {
    float v = (float)pre16[pb + (size_t)w2 * OCH] + xt[w2][oc];
    v = (v - mu) * rs * gg + bb;
    xt[w2][oc] = fminf(fmaxf(v, -1.f), 1.f);   // in-place: col oc owned by thread
  }
  __syncthreads();
  for (int k = 0; k < 32; ++k) {
    int oc2 = og * 32 + k;
    out[((size_t)(n * 256 + oc2) * 32 + h) * 32 + w] = xt[w][oc2];
  }
  if (blk == 0 && t == 0) out[8388608] = r0[0] + 8.625f;
}

extern "C" void kernel_launch(void* const* d_in, const int* in_sizes, int n_in,
                              void* d_out, int out_size, void* d_ws, size_t ws_size,
                              hipStream_t stream) {
  const float* x0   = (const float*)d_in[0];
  const float* reg0 = (const float*)d_in[1];
  const float* w1   = (const float*)d_in[2];
  const float* g1   = (const float*)d_in[3];
  const float* b1   = (const float*)d_in[4];
  const float* w2   = (const float*)d_in[5];
  const float* g2   = (const float*)d_in[6];
  const float* b2   = (const float*)d_in[7];

  char* ws = (char*)d_ws;
  u64*   Wbits = (u64*)(ws);                        // 147456 B
  u64*   masks = (u64*)(ws + 147456);               // 2592 B
  float* st    = (float*)(ws + 151552);             // 4 KiB
  u64*   Sb    = (u64*)(ws + 155648);               // 1 MiB
  u64*   Pw    = (u64*)(ws + 1204224);              // 9437184 B
  short* v16   = (short*)(ws + 10641408);           // 16777216 B
  short* pre16 = (short*)(ws + 27418624);           // 16777216 B

  bb_init   <<<1,    256, 0, stream>>>(st, masks);
  bb_wbits  <<<4608, 256, 0, stream>>>(w1, w2, Wbits);
  bb_xbits  <<<1024, 256, 0, stream>>>(x0, Sb);
  bb_patch  <<<4608, 256, 0, stream>>>(Sb, Pw);
  bb_conv   <<<dim3(256, 4), 256, 0, stream>>>(Pw, Wbits, masks, v16);
  bb_stats1 <<<256,  256, 0, stream>>>(v16, st);
  bb_xbits2 <<<1024, 256, 0, stream>>>(v16, st, g1, b1, Sb);
  bb_patch  <<<4608, 256, 0, stream>>>(Sb, Pw);
  bb_conv   <<<dim3(256, 4), 256, 0, stream>>>(Pw, Wbits + OCH * NCH, masks, pre16);
  bb_stats2t<<<1024, 256, 0, stream>>>(pre16, x0, st);
  bb_fint   <<<1024, 256, 0, stream>>>(pre16, x0, st, g2, b2, reg0, (float*)d_out);
}